// Round 1
// baseline (829.823 us; speedup 1.0000x reference)
//
#include <hip/hip_runtime.h>
#include <stdint.h>

// CrossAttention seq-len-1: softmax over singleton axis == 1, so attention
// reduces to   attn = x_other @ (out_w @ wv).T + (out_w @ bv + out_b).
// Pipeline per stream: combined-GEMM -> add+LN -> relu-GEMM -> GEMM(->d_out) -> add+LN in-place.
// All GEMMs bf16 MFMA (16x16x32), fp32 accumulate. Threshold is bf16-floor (0.111).

#define E 512
#define LNEPS 1e-5f

typedef unsigned short u16;
using u16x8   = __attribute__((ext_vector_type(8))) u16;
using shortx8 = __attribute__((ext_vector_type(8))) short;
using floatx4 = __attribute__((ext_vector_type(4))) float;

__device__ __forceinline__ float bf2f(u16 u) {
  uint32_t x = ((uint32_t)u) << 16;
  return __builtin_bit_cast(float, x);
}
__device__ __forceinline__ u16 f2bf(float f) {  // round-to-nearest-even
  uint32_t x = __builtin_bit_cast(uint32_t, f);
  x += 0x7fffu + ((x >> 16) & 1u);
  return (u16)(x >> 16);
}

__device__ __forceinline__ void gl_lds16(const u16* g, u16* l) {
  // async global->LDS, 16B per lane; LDS dest = wave-uniform base + lane*16
  __builtin_amdgcn_global_load_lds(
      (__attribute__((address_space(1))) uint32_t*)g,
      (__attribute__((address_space(3))) uint32_t*)l, 16, 0, 0);
}

// C[m,n] = sum_k A[m,k]*W[n,k] + bias[n]   (A: MxK bf16, W: NxK bf16 row-major)
// 128x128 block tile, BK=32, 4 waves each 64x64 (4x4 MFMA 16x16x32 tiles).
template <bool RELU, bool OUTF32>
__global__ __launch_bounds__(256) void gemm_bt(const u16* __restrict__ A,
                                               const u16* __restrict__ W,
                                               const float* __restrict__ bias,
                                               void* __restrict__ Cout,
                                               int M, int N, int K, int ldc) {
  __shared__ u16 sA[128 * 32];
  __shared__ u16 sB[128 * 32];
  const int tid  = threadIdx.x;
  const int wave = tid >> 6;
  const int lane = tid & 63;
  const int m0 = blockIdx.x * 128;
  const int n0 = blockIdx.y * 128;
  const int wm = (wave >> 1) * 64;
  const int wn = (wave & 1) * 64;
  const int fm   = lane & 15;
  const int quad = lane >> 4;

  const floatx4 zero = {0.f, 0.f, 0.f, 0.f};
  floatx4 acc[4][4];
#pragma unroll
  for (int i = 0; i < 4; ++i)
#pragma unroll
    for (int j = 0; j < 4; ++j) acc[i][j] = zero;

  // staging map: elem o = wave*512 + lane*8 (+2048 for issue 1); row=o/32, col=o%32
  const int o0 = wave * 512 + lane * 8;
  const int r0 = o0 >> 5;
  const int c0 = o0 & 31;
  const u16* Ap = A + (size_t)(m0 + r0) * K + c0;
  const u16* Wp = W + (size_t)(n0 + r0) * K + c0;
  const size_t skip = (size_t)64 * K;  // +64 rows for issue 1
  u16* sAd = sA + wave * 512;
  u16* sBd = sB + wave * 512;

  for (int k0 = 0; k0 < K; k0 += 32) {
    __syncthreads();
    gl_lds16(Ap, sAd);
    gl_lds16(Ap + skip, sAd + 2048);
    gl_lds16(Wp, sBd);
    gl_lds16(Wp + skip, sBd + 2048);
    Ap += 32;
    Wp += 32;
    __syncthreads();  // drains vmcnt: LDS now holds the tiles
    shortx8 af[4], bf[4];
#pragma unroll
    for (int i = 0; i < 4; ++i) {
      af[i] = *(const shortx8*)(sA + (wm + i * 16 + fm) * 32 + quad * 8);
      bf[i] = *(const shortx8*)(sB + (wn + i * 16 + fm) * 32 + quad * 8);
    }
#pragma unroll
    for (int i = 0; i < 4; ++i)
#pragma unroll
      for (int j = 0; j < 4; ++j)
        acc[i][j] = __builtin_amdgcn_mfma_f32_16x16x32_bf16(af[i], bf[j], acc[i][j], 0, 0, 0);
  }

  // epilogue: C/D layout col=lane&15, row=quad*4+reg  (m89/m91 verified)
#pragma unroll
  for (int j = 0; j < 4; ++j) {
    const int col = n0 + wn + j * 16 + fm;
    const float bj = bias ? bias[col] : 0.f;
#pragma unroll
    for (int i = 0; i < 4; ++i) {
      const int rb = m0 + wm + i * 16 + quad * 4;
#pragma unroll
      for (int r = 0; r < 4; ++r) {
        float v = acc[i][j][r] + bj;
        if (RELU) v = fmaxf(v, 0.f);
        if (OUTF32)
          ((float*)Cout)[(size_t)(rb + r) * ldc + col] = v;
        else
          ((u16*)Cout)[(size_t)(rb + r) * ldc + col] = f2bf(v);
      }
    }
  }
}

// MODE 0: out_bf16[row*E] = LN(resid_f32[row*E] + add_bf16[row*E])
// MODE 1: out_f32[row*ld] = LN(resid_bf16[row*E] + add_f32[row*ld])   (in-place on d_out ok)
// one wave per row of 512; lane handles 8 consecutive elements
template <int MODE>
__global__ __launch_bounds__(256) void ln_add_kernel(const void* __restrict__ resid,
                                                     const void* __restrict__ addv,
                                                     const float* __restrict__ g,
                                                     const float* __restrict__ b,
                                                     void* __restrict__ outp, int ld) {
  const int wave = threadIdx.x >> 6;
  const int lane = threadIdx.x & 63;
  const size_t row = (size_t)blockIdx.x * 4 + wave;
  const int col = lane * 8;
  float x[8];
  if (MODE == 0) {
    const float* rp = (const float*)resid + row * E + col;
    const u16x8 a = *(const u16x8*)((const u16*)addv + row * E + col);
    const float4 r0 = *(const float4*)rp;
    const float4 r1 = *(const float4*)(rp + 4);
    x[0] = r0.x + bf2f(a[0]); x[1] = r0.y + bf2f(a[1]);
    x[2] = r0.z + bf2f(a[2]); x[3] = r0.w + bf2f(a[3]);
    x[4] = r1.x + bf2f(a[4]); x[5] = r1.y + bf2f(a[5]);
    x[6] = r1.z + bf2f(a[6]); x[7] = r1.w + bf2f(a[7]);
  } else {
    const u16x8 a = *(const u16x8*)((const u16*)resid + row * E + col);
    const float* ap = (const float*)addv + row * ld + col;
    const float4 r0 = *(const float4*)ap;
    const float4 r1 = *(const float4*)(ap + 4);
    x[0] = r0.x + bf2f(a[0]); x[1] = r0.y + bf2f(a[1]);
    x[2] = r0.z + bf2f(a[2]); x[3] = r0.w + bf2f(a[3]);
    x[4] = r1.x + bf2f(a[4]); x[5] = r1.y + bf2f(a[5]);
    x[6] = r1.z + bf2f(a[6]); x[7] = r1.w + bf2f(a[7]);
  }
  float s = 0.f, sq = 0.f;
#pragma unroll
  for (int i = 0; i < 8; ++i) {
    s += x[i];
    sq += x[i] * x[i];
  }
#pragma unroll
  for (int off = 32; off > 0; off >>= 1) {
    s += __shfl_xor(s, off);
    sq += __shfl_xor(sq, off);
  }
  const float mean = s * (1.f / E);
  const float var = sq * (1.f / E) - mean * mean;
  const float rs = rsqrtf(var + LNEPS);
  const float4 g0 = *(const float4*)(g + col);
  const float4 g1 = *(const float4*)(g + col + 4);
  const float4 b0 = *(const float4*)(b + col);
  const float4 b1 = *(const float4*)(b + col + 4);
  float y[8];
  y[0] = (x[0] - mean) * rs * g0.x + b0.x;
  y[1] = (x[1] - mean) * rs * g0.y + b0.y;
  y[2] = (x[2] - mean) * rs * g0.z + b0.z;
  y[3] = (x[3] - mean) * rs * g0.w + b0.w;
  y[4] = (x[4] - mean) * rs * g1.x + b1.x;
  y[5] = (x[5] - mean) * rs * g1.y + b1.y;
  y[6] = (x[6] - mean) * rs * g1.z + b1.z;
  y[7] = (x[7] - mean) * rs * g1.w + b1.w;
  if (MODE == 0) {
    u16x8 o;
#pragma unroll
    for (int i = 0; i < 8; ++i) o[i] = f2bf(y[i]);
    *(u16x8*)((u16*)outp + row * E + col) = o;
  } else {
    float* op = (float*)outp + row * ld + col;
    *(float4*)op = make_float4(y[0], y[1], y[2], y[3]);
    *(float4*)(op + 4) = make_float4(y[4], y[5], y[6], y[7]);
  }
}

__global__ __launch_bounds__(256) void cast_kernel(const float* __restrict__ in,
                                                   u16* __restrict__ out) {
  const size_t i = ((size_t)blockIdx.x * 256 + threadIdx.x) * 8;
  const float4 a = *(const float4*)(in + i);
  const float4 c = *(const float4*)(in + i + 4);
  u16x8 o;
  o[0] = f2bf(a.x); o[1] = f2bf(a.y); o[2] = f2bf(a.z); o[3] = f2bf(a.w);
  o[4] = f2bf(c.x); o[5] = f2bf(c.y); o[6] = f2bf(c.z); o[7] = f2bf(c.w);
  *(u16x8*)(out + i) = o;
}

// out[k][j] = bf16(in[j][k]) for ExE
__global__ __launch_bounds__(256) void transpose_cast_kernel(const float* __restrict__ in,
                                                             u16* __restrict__ out) {
  __shared__ float t[32][33];
  const int bx = blockIdx.x * 32;
  const int by = blockIdx.y * 32;
  const int x = threadIdx.x & 31;
  const int y0 = threadIdx.x >> 5;
#pragma unroll
  for (int y = y0; y < 32; y += 8) t[y][x] = in[(size_t)(by + y) * E + bx + x];
  __syncthreads();
#pragma unroll
  for (int y = y0; y < 32; y += 8) out[(size_t)(bx + y) * E + by + x] = f2bf(t[x][y]);
}

// bc[n] = dot(outw[n,:], bv) + outb[n]
__global__ __launch_bounds__(256) void combine_bias_kernel(const float* __restrict__ outw,
                                                           const float* __restrict__ bv,
                                                           const float* __restrict__ outb,
                                                           float* __restrict__ bc) {
  const int n = blockIdx.x * 256 + threadIdx.x;
  const float* wr = outw + (size_t)n * E;
  float s = 0.f;
  for (int j = 0; j < E; j += 4) {
    const float4 w4 = *(const float4*)(wr + j);
    const float4 v4 = *(const float4*)(bv + j);
    s += w4.x * v4.x + w4.y * v4.y + w4.z * v4.z + w4.w * v4.w;
  }
  bc[n] = s + outb[n];
}

extern "C" void kernel_launch(void* const* d_in, const int* in_sizes, int n_in,
                              void* d_out, int out_size, void* d_ws, size_t ws_size,
                              hipStream_t stream) {
  const float* dna      = (const float*)d_in[0];
  const float* mol      = (const float*)d_in[1];
  const float* a1_in_w  = (const float*)d_in[2];
  const float* a1_in_b  = (const float*)d_in[3];
  const float* a1_out_w = (const float*)d_in[4];
  const float* a1_out_b = (const float*)d_in[5];
  const float* a2_in_w  = (const float*)d_in[6];
  const float* a2_in_b  = (const float*)d_in[7];
  const float* a2_out_w = (const float*)d_in[8];
  const float* a2_out_b = (const float*)d_in[9];
  const float* ln1_g = (const float*)d_in[10];
  const float* ln1_b = (const float*)d_in[11];
  const float* ln2_g = (const float*)d_in[12];
  const float* ln2_b = (const float*)d_in[13];
  const float* ln3_g = (const float*)d_in[14];
  const float* ln3_b = (const float*)d_in[15];
  const float* ln4_g = (const float*)d_in[16];
  const float* ln4_b = (const float*)d_in[17];
  const float* f1_w1 = (const float*)d_in[18];
  const float* f1_b1 = (const float*)d_in[19];
  const float* f1_w2 = (const float*)d_in[20];
  const float* f1_b2 = (const float*)d_in[21];
  const float* f2_w1 = (const float*)d_in[22];
  const float* f2_b1 = (const float*)d_in[23];
  const float* f2_w2 = (const float*)d_in[24];
  const float* f2_b2 = (const float*)d_in[25];

  const int M = in_sizes[0] / E;  // 32768

  char* ws = (char*)d_ws;
  auto bump = [&](size_t sz) {
    char* p = ws;
    ws += (sz + 255) & ~(size_t)255;
    return p;
  };
  u16* wvT1   = (u16*)bump((size_t)E * E * 2);
  u16* wvT2   = (u16*)bump((size_t)E * E * 2);
  u16* outw1b = (u16*)bump((size_t)E * E * 2);
  u16* outw2b = (u16*)bump((size_t)E * E * 2);
  u16* Wc1    = (u16*)bump((size_t)E * E * 2);
  u16* Wc2    = (u16*)bump((size_t)E * E * 2);
  u16* fw11   = (u16*)bump((size_t)2 * E * E * 2);
  u16* fw12   = (u16*)bump((size_t)2 * E * E * 2);
  u16* fw21   = (u16*)bump((size_t)2 * E * E * 2);
  u16* fw22   = (u16*)bump((size_t)2 * E * E * 2);
  float* bc1  = (float*)bump(E * 4);
  float* bc2  = (float*)bump(E * 4);
  u16* X1 = (u16*)bump((size_t)M * E * 2);      // dna_bf, later y1
  u16* X2 = (u16*)bump((size_t)M * E * 2);      // mol_bf, later y2
  u16* Hb = (u16*)bump((size_t)M * 2 * E * 2);  // attnA|attnB, later FFN hidden
  u16* H0 = Hb;
  u16* H1 = Hb + (size_t)M * E;
  float* out_f = (float*)d_out;  // M x 2E, left=dna stream, right=mol stream

  // ---- weight prep (runs every call; ~7 MB of ws) ----
  transpose_cast_kernel<<<dim3(16, 16), 256, 0, stream>>>(a1_in_w + 2 * E * E, wvT1);
  transpose_cast_kernel<<<dim3(16, 16), 256, 0, stream>>>(a2_in_w + 2 * E * E, wvT2);
  cast_kernel<<<E * E / 2048, 256, 0, stream>>>(a1_out_w, outw1b);
  cast_kernel<<<E * E / 2048, 256, 0, stream>>>(a2_out_w, outw2b);
  cast_kernel<<<2 * E * E / 2048, 256, 0, stream>>>(f1_w1, fw11);
  cast_kernel<<<2 * E * E / 2048, 256, 0, stream>>>(f1_w2, fw12);
  cast_kernel<<<2 * E * E / 2048, 256, 0, stream>>>(f2_w1, fw21);
  cast_kernel<<<2 * E * E / 2048, 256, 0, stream>>>(f2_w2, fw22);
  combine_bias_kernel<<<2, 256, 0, stream>>>(a1_out_w, a1_in_b + 2 * E, a1_out_b, bc1);
  combine_bias_kernel<<<2, 256, 0, stream>>>(a2_out_w, a2_in_b + 2 * E, a2_out_b, bc2);
  // Wc[n,k] = sum_j out_w[n,j] * wv[j,k]  via gemm_bt(out_w, wv^T)
  gemm_bt<false, false><<<dim3(4, 4), 256, 0, stream>>>(outw1b, wvT1, nullptr, Wc1, E, E, E, E);
  gemm_bt<false, false><<<dim3(4, 4), 256, 0, stream>>>(outw2b, wvT2, nullptr, Wc2, E, E, E, E);

  // ---- activations ----
  cast_kernel<<<(int)((size_t)M * E / 2048), 256, 0, stream>>>(dna, X1);
  cast_kernel<<<(int)((size_t)M * E / 2048), 256, 0, stream>>>(mol, X2);
  // attn (softmax==1 -> pure projection with combined weights)
  gemm_bt<false, false><<<dim3(M / 128, 4), 256, 0, stream>>>(X2, Wc1, bc1, H0, M, E, E, E);
  gemm_bt<false, false><<<dim3(M / 128, 4), 256, 0, stream>>>(X1, Wc2, bc2, H1, M, E, E, E);
  // y = LN(x + attn)  (overwrites the now-dead bf16 input casts)
  ln_add_kernel<0><<<M / 4, 256, 0, stream>>>(dna, H0, ln1_g, ln1_b, X1, E);
  ln_add_kernel<0><<<M / 4, 256, 0, stream>>>(mol, H1, ln2_g, ln2_b, X2, E);
  // stream A FFN + final LN (in-place on d_out left half)
  gemm_bt<true, false><<<dim3(M / 128, 8), 256, 0, stream>>>(X1, fw11, f1_b1, Hb, M, 2 * E, E, 2 * E);
  gemm_bt<false, true><<<dim3(M / 128, 4), 256, 0, stream>>>(Hb, fw12, f1_b2, out_f, M, E, 2 * E, 2 * E);
  ln_add_kernel<1><<<M / 4, 256, 0, stream>>>(X1, out_f, ln3_g, ln3_b, out_f, 2 * E);
  // stream B FFN + final LN (in-place on d_out right half)
  gemm_bt<true, false><<<dim3(M / 128, 8), 256, 0, stream>>>(X2, fw21, f2_b1, Hb, M, 2 * E, E, 2 * E);
  gemm_bt<false, true><<<dim3(M / 128, 4), 256, 0, stream>>>(Hb, fw22, f2_b2, out_f + E, M, E, 2 * E, 2 * E);
  ln_add_kernel<1><<<M / 4, 256, 0, stream>>>(X2, out_f + E, ln4_g, ln4_b, out_f + E, 2 * E);
}